// Round 1
// baseline (77.457 us; speedup 1.0000x reference)
//
#include <hip/hip_runtime.h>

// SpatialLoss: x [64,16,256,256] f32 -> scalar
// loss = sum_{(i,j) in [-2,2]^2 \ (0,0)} (1/sqrt(i^2+j^2)) * sum((x shifted diff)^2) / 64 / 256 / 256
// Symmetry (i,j) <-> (-i,-j): compute 12 half-space offsets with coeff 2/w.

#define RR 256
#define CCOLS 256
#define NPLANES 1024   // 64*16

__device__ __forceinline__ void load_row(const float* __restrict__ rowp, int sc, float (&W)[20]) {
    // window covers cols c0-2 .. c0+17 (clamped at plane edges; clamped values are masked out)
    const int c0 = sc << 4;
    const int lo = (sc == 0) ? 0 : (c0 - 2);
    const int hi = (sc == 15) ? (CCOLS - 2) : (c0 + 16);
    float2 l2 = *reinterpret_cast<const float2*>(rowp + lo);
    float4 q0 = *reinterpret_cast<const float4*>(rowp + c0);
    float4 q1 = *reinterpret_cast<const float4*>(rowp + c0 + 4);
    float4 q2 = *reinterpret_cast<const float4*>(rowp + c0 + 8);
    float4 q3 = *reinterpret_cast<const float4*>(rowp + c0 + 12);
    float2 h2 = *reinterpret_cast<const float2*>(rowp + hi);
    W[0]=l2.x;  W[1]=l2.y;
    W[2]=q0.x;  W[3]=q0.y;  W[4]=q0.z;  W[5]=q0.w;
    W[6]=q1.x;  W[7]=q1.y;  W[8]=q1.z;  W[9]=q1.w;
    W[10]=q2.x; W[11]=q2.y; W[12]=q2.z; W[13]=q2.w;
    W[14]=q3.x; W[15]=q3.y; W[16]=q3.z; W[17]=q3.w;
    W[18]=h2.x; W[19]=h2.y;
}

// A = row r, B = row r+1, C = row r+2. Center value for element k is A[k+2].
// Neighbor (k, j) lives at W[k+2+j]. Col masks: k+j<0 -> mL, k+j>15 -> mR (static per (k,j)).
template<bool EDGE>
__device__ __forceinline__ void accum(const float (&A)[20], const float (&B)[20], const float (&C)[20],
                                      float mL, float mR, float mB, float mC,
                                      float &a1, float &a2, float &a4, float &a5, float &a8)
{
#pragma unroll
    for (int k = 0; k < 16; ++k) {
        const float v = A[k + 2];
        // row A (i=0): j=1 (w=1), j=2 (w=2)
        {
            float d1 = A[k + 3] - v; if (k == 15) d1 *= mR;
            float d2 = A[k + 4] - v; if (k >= 14) d2 *= mR;
            a1 = fmaf(d1, d1, a1);
            a4 = fmaf(d2, d2, a4);
        }
        // row B (i=1): j=0 (w=1), j=+-1 (w=sqrt2), j=+-2 (w=sqrt5)
        {
            float d0  = B[k + 2] - v;
            float dm1 = B[k + 1] - v; if (k == 0)  dm1 *= mL;
            float dp1 = B[k + 3] - v; if (k == 15) dp1 *= mR;
            float dm2 = B[k + 0] - v; if (k <= 1)  dm2 *= mL;
            float dp2 = B[k + 4] - v; if (k >= 14) dp2 *= mR;
            if (EDGE) { d0 *= mB; dm1 *= mB; dp1 *= mB; dm2 *= mB; dp2 *= mB; }
            a1 = fmaf(d0,  d0,  a1);
            a2 = fmaf(dm1, dm1, a2);
            a2 = fmaf(dp1, dp1, a2);
            a5 = fmaf(dm2, dm2, a5);
            a5 = fmaf(dp2, dp2, a5);
        }
        // row C (i=2): j=0 (w=2), j=+-1 (w=sqrt5), j=+-2 (w=sqrt8)
        {
            float d0  = C[k + 2] - v;
            float dm1 = C[k + 1] - v; if (k == 0)  dm1 *= mL;
            float dp1 = C[k + 3] - v; if (k == 15) dp1 *= mR;
            float dm2 = C[k + 0] - v; if (k <= 1)  dm2 *= mL;
            float dp2 = C[k + 4] - v; if (k >= 14) dp2 *= mR;
            if (EDGE) { d0 *= mC; dm1 *= mC; dp1 *= mC; dm2 *= mC; dp2 *= mC; }
            a4 = fmaf(d0,  d0,  a4);
            a5 = fmaf(dm1, dm1, a5);
            a5 = fmaf(dp1, dp1, a5);
            a8 = fmaf(dm2, dm2, a8);
            a8 = fmaf(dp2, dp2, a8);
        }
    }
}

__global__ __launch_bounds__(256) void spatial_loss_partial(const float* __restrict__ x,
                                                            float* __restrict__ partial)
{
    const int p   = blockIdx.x;           // plane 0..1023
    const int tid = threadIdx.x;
    const int sr  = tid >> 4;             // strip row 0..15 (16 rows each)
    const int sc  = tid & 15;             // strip col 0..15 (16 cols each)
    const float* plane = x + (size_t)p * (RR * CCOLS);
    const int r0 = sr << 4;

    float A[20], B[20], C[20];
    load_row(plane + (size_t)(r0    ) * CCOLS, sc, A);
    load_row(plane + (size_t)(r0 + 1) * CCOLS, sc, B);
    load_row(plane + (size_t)(r0 + 2) * CCOLS, sc, C);

    const float mL = (sc == 0)  ? 0.f : 1.f;
    const float mR = (sc == 15) ? 0.f : 1.f;

    float a1 = 0.f, a2 = 0.f, a4 = 0.f, a5 = 0.f, a8 = 0.f;

#pragma unroll 4
    for (int i = 0; i < 16; ++i) {
        const int r = r0 + i;
        if (i < 14) {
            accum<false>(A, B, C, mL, mR, 1.f, 1.f, a1, a2, a4, a5, a8);
        } else {
            // only the statically-last 2 iterations can hit the bottom edge (sr==15);
            // for sr<15 the masks evaluate to 1.0 and stay correct.
            const float mB = (r + 1 < RR) ? 1.f : 0.f;
            const float mC = (r + 2 < RR) ? 1.f : 0.f;
            accum<true>(A, B, C, mL, mR, mB, mC, a1, a2, a4, a5, a8);
        }
        if (i < 15) {
#pragma unroll
            for (int q = 0; q < 20; ++q) { A[q] = B[q]; B[q] = C[q]; }
            int rn = r0 + i + 3; if (rn > RR - 1) rn = RR - 1;   // clamped rows are masked
            load_row(plane + (size_t)rn * CCOLS, sc, C);
        }
    }

    // coefficients 2/w per weight class
    float loss = 2.0f * a1
               + 1.41421356237309515f  * a2     // 2/sqrt(2)
               + 1.0f                  * a4     // 2/2
               + 0.894427190999915878f * a5     // 2/sqrt(5)
               + 0.707106781186547573f * a8;    // 2/sqrt(8)

    // wave (64) reduce, then block reduce
    #pragma unroll
    for (int off = 32; off; off >>= 1) loss += __shfl_down(loss, off, 64);
    __shared__ float wsum[4];
    const int wave = tid >> 6, lane = tid & 63;
    if (lane == 0) wsum[wave] = loss;
    __syncthreads();
    if (tid == 0) partial[p] = wsum[0] + wsum[1] + wsum[2] + wsum[3];
}

__global__ __launch_bounds__(256) void reduce_partials(const float* __restrict__ partial,
                                                       float* __restrict__ out)
{
    const int tid = threadIdx.x;
    float s = partial[tid] + partial[tid + 256] + partial[tid + 512] + partial[tid + 768];
    #pragma unroll
    for (int off = 32; off; off >>= 1) s += __shfl_down(s, off, 64);
    __shared__ float wsum[4];
    if ((tid & 63) == 0) wsum[tid >> 6] = s;
    __syncthreads();
    if (tid == 0) out[0] = (wsum[0] + wsum[1] + wsum[2] + wsum[3]) * (1.0f / 4194304.0f);
}

extern "C" void kernel_launch(void* const* d_in, const int* in_sizes, int n_in,
                              void* d_out, int out_size, void* d_ws, size_t ws_size,
                              hipStream_t stream) {
    const float* x = (const float*)d_in[0];
    float* out     = (float*)d_out;
    float* partial = (float*)d_ws;   // 1024 floats = 4 KB
    spatial_loss_partial<<<NPLANES, 256, 0, stream>>>(x, partial);
    reduce_partials<<<1, 256, 0, stream>>>(partial, out);
}